// Round 7
// baseline (74.919 us; speedup 1.0000x reference)
//
#include <hip/hip_runtime.h>

// RankLoss, triangle + poly-log, log2-domain, packed-fp32, 1-wave blocks.
//   per unordered pair {i,j}: logsig = min(sd,0) - ln(1+e^{-|d|}),
//   d = p[i]-p[j], sd = (t[i]<t[j] ? d : -d).
// Work in d' = d*log2e: u = e^{-|d|} = 2^{-|d'|}; min(sd,0) = ln2*min(sd',0).
// ln(1+u) ~= B0 + u*q(u) on [0,1] (deg-5, |err|<=1.5e-5); B0*count + ln2
// folded into finalize. count = C(8192,2) analytic (ties measure-zero).
// TI=64, 64-thread blocks: 8256 waves -> up to 8 waves/SIMD for latency hiding.

#define N 8192
#define TI 64
#define NB (N / TI)                  // 128
#define NTILES (NB * (NB + 1) / 2)   // 8256
#define LOG2E 1.4426950408889634f

#define B0 (-1.084e-05f)
#define B1 ( 0.99923144f)
#define B2 (-0.49021708f)
#define B3 ( 0.28525664f)
#define B4 (-0.13157376f)
#define B5 ( 0.03044704f)

typedef float f2 __attribute__((ext_vector_type(2)));

__global__ __launch_bounds__(TI) void rankloss_tri(
    const float* __restrict__ preds, const float* __restrict__ tgts,
    float2* __restrict__ pout)
{
    __shared__ float sp[TI];   // p*log2e contiguous -> float4 = 2 packed pairs
    __shared__ float st_[TI];  // t contiguous
    const int tid = threadIdx.x;
    const int u = blockIdx.x;

    // decode triangular tile index: u = jb*(jb+1)/2 + ib, ib <= jb
    int jb = (int)((sqrtf(8.0f * (float)u + 1.0f) - 1.0f) * 0.5f);
    while ((jb + 1) * (jb + 2) / 2 <= u) ++jb;
    while (jb * (jb + 1) / 2 > u) --jb;
    const int ib = u - jb * (jb + 1) / 2;

    const int i  = ib * TI + tid;
    const int j0 = jb * TI;

    sp[tid]  = preds[j0 + tid] * LOG2E;
    st_[tid] = tgts[j0 + tid];
    __syncthreads();

    const float pi = preds[i] * LOG2E;
    const float ti = tgts[i];
    const f2 pip2 = {pi, pi};
    const f2 c5 = {B5, B5}, c4 = {B4, B4}, c3 = {B3, B3}, c2 = {B2, B2}, c1 = {B1, B1};

    f2 sta = {0.f, 0.f}, stb = {0.f, 0.f};
    f2 sla = {0.f, 0.f}, slb = {0.f, 0.f};

    const float4* p4 = (const float4*)sp;
    const float4* t4 = (const float4*)st_;

    if (ib != jb) {
        #pragma unroll
        for (int kk = 0; kk < TI / 4; ++kk) {
            const float4 pv = p4[kk];   // uniform addr -> LDS broadcast
            const float4 tv = t4[kk];
            {
                f2 pj = {pv.x, pv.y};
                f2 dp = pip2 - pj;
                f2 uu = {__builtin_amdgcn_exp2f(-fabsf(dp.x)),
                         __builtin_amdgcn_exp2f(-fabsf(dp.y))};
                f2 q = __builtin_elementwise_fma(c5, uu, c4);
                q = __builtin_elementwise_fma(q, uu, c3);
                q = __builtin_elementwise_fma(q, uu, c2);
                q = __builtin_elementwise_fma(q, uu, c1);
                sla = __builtin_elementwise_fma(q, uu, sla);
                f2 sd;
                sd.x = fminf((ti < tv.x) ? dp.x : -dp.x, 0.f);
                sd.y = fminf((ti < tv.y) ? dp.y : -dp.y, 0.f);
                sta += sd;
            }
            {
                f2 pj = {pv.z, pv.w};
                f2 dp = pip2 - pj;
                f2 uu = {__builtin_amdgcn_exp2f(-fabsf(dp.x)),
                         __builtin_amdgcn_exp2f(-fabsf(dp.y))};
                f2 q = __builtin_elementwise_fma(c5, uu, c4);
                q = __builtin_elementwise_fma(q, uu, c3);
                q = __builtin_elementwise_fma(q, uu, c2);
                q = __builtin_elementwise_fma(q, uu, c1);
                slb = __builtin_elementwise_fma(q, uu, slb);
                f2 sd;
                sd.x = fminf((ti < tv.z) ? dp.x : -dp.x, 0.f);
                sd.y = fminf((ti < tv.w) ? dp.y : -dp.y, 0.f);
                stb += sd;
            }
        }
    } else {
        // diagonal tile: only j = k > i = tid contributes
        #pragma unroll 4
        for (int k = 0; k < TI; ++k) {
            const float pj = sp[k];
            const float tj = st_[k];
            const float dp = pi - pj;
            float uu = __builtin_amdgcn_exp2f(-fabsf(dp));
            float sd = fminf((ti < tj) ? dp : -dp, 0.f);
            const bool valid = (k > tid);
            uu = valid ? uu : 0.f;
            sd = valid ? sd : 0.f;
            float q = __builtin_fmaf(B5, uu, B4);
            q = __builtin_fmaf(q, uu, B3);
            q = __builtin_fmaf(q, uu, B2);
            q = __builtin_fmaf(q, uu, B1);
            sla.x = __builtin_fmaf(q, uu, sla.x);
            sta.x += sd;
        }
    }

    float stt = sta.x + sta.y + stb.x + stb.y;
    float sll = sla.x + sla.y + slb.x + slb.y;
    for (int off = 32; off > 0; off >>= 1) {
        stt += __shfl_down(stt, off, 64);
        sll += __shfl_down(sll, off, 64);
    }
    if (tid == 0) pout[blockIdx.x] = make_float2(stt, sll);
}

__global__ __launch_bounds__(256) void rankloss_final(
    const float2* __restrict__ pout, float* __restrict__ out)
{
    const int tid = threadIdx.x;
    double st = 0.0, sl = 0.0;
    for (int b = tid; b < NTILES; b += 256) {
        const float2 v = pout[b];
        st += (double)v.x;
        sl += (double)v.y;
    }
    for (int off = 32; off > 0; off >>= 1) {
        st += __shfl_down(st, off, 64);
        sl += __shfl_down(sl, off, 64);
    }
    __shared__ double wst[4], wsl[4];
    const int wave = tid >> 6;
    if ((tid & 63) == 0) { wst[wave] = st; wsl[wave] = sl; }
    __syncthreads();
    if (tid == 0) {
        double St = 0.0, Sl = 0.0;
        #pragma unroll
        for (int w = 0; w < 4; ++w) { St += wst[w]; Sl += wsl[w]; }
        const double count = 33550336.0;          // C(8192,2)
        const double ln2   = 0.6931471805599453;
        out[0] = (float)((St * ln2 - Sl - (double)B0 * count) / count);
    }
}

extern "C" void kernel_launch(void* const* d_in, const int* in_sizes, int n_in,
                              void* d_out, int out_size, void* d_ws, size_t ws_size,
                              hipStream_t stream) {
    const float* preds = (const float*)d_in[0];
    const float* tgts  = (const float*)d_in[1];
    float2* pout = (float2*)d_ws;   // NTILES float2 = 66 KB, fully written by tri

    rankloss_tri<<<NTILES, TI, 0, stream>>>(preds, tgts, pout);
    rankloss_final<<<1, 256, 0, stream>>>(pout, (float*)d_out);
}

// Round 8
// 71.686 us; speedup vs baseline: 1.0451x; 1.0451x over previous
//
#include <hip/hip_runtime.h>

// RankLoss, triangle + LDS-table softplus (NO transcendentals in inner loop).
//   per unordered pair {i,j}: logsig = min(sd,0) - ln(1+e^{-|d|}),
//   d = p[i]-p[j], sd = (t[i]<t[j] ? d : -d).  count = C(8192,2) analytic.
// Work in table units: d'' = d * 32*log2e. Then
//   softplus_ln = ln2 * log2(1+2^{-|d''|/32})  -> table T[k]=log2(1+2^{-k/32}),
//   linear interp at |d''| (step=1 table unit = 1/32 exp2-unit; err<=3e-5).
//   min(sd,0)_ln = (ln2/32) * min(sd'',0).
// Trans pipe measured ~30cyc/wave64 per v_exp/v_log (R1/R5 fit) -> table wins.

#define N 8192
#define TI 128
#define NB (N / TI)                  // 64
#define NTILES (NB * (NB + 1) / 2)   // 2080
#define SCALE 46.166241308446828f    // 32*log2(e)
#define TBLN 640                     // built entries (covers idx 0..512+)
#define CLAMPV 511.5f                // max table coord (idx<=511, T[512] valid)

__global__ __launch_bounds__(TI) void rankloss_tri(
    const float* __restrict__ preds, const float* __restrict__ tgts,
    float2* __restrict__ pout)
{
    __shared__ float tbl[TBLN];
    const int tid = threadIdx.x;
    const int u = blockIdx.x;

    // build softplus table: T[k] = log2(1 + 2^{-k/32})
    #pragma unroll
    for (int k = tid; k < TBLN; k += TI) {
        const float a = (float)k * (1.0f / 32.0f);
        tbl[k] = __log2f(1.0f + __builtin_amdgcn_exp2f(-a));
    }

    // decode triangular tile index: u = jb*(jb+1)/2 + ib, ib <= jb
    int jb = (int)((sqrtf(8.0f * (float)u + 1.0f) - 1.0f) * 0.5f);
    while ((jb + 1) * (jb + 2) / 2 <= u) ++jb;
    while (jb * (jb + 1) / 2 > u) --jb;
    const int ib = u - jb * (jb + 1) / 2;

    const int i  = ib * TI + tid;
    const int j0 = jb * TI;

    const float pi = preds[i] * SCALE;   // i-value in table units
    const float ti = tgts[i];
    const float* __restrict__ pj_base = preds + j0;   // block-uniform -> s_load
    const float* __restrict__ tj_base = tgts  + j0;

    __syncthreads();   // table ready

    float st  = 0.f;   // sum min(sd'',0)          (table units)
    float sl0 = 0.f;   // sum T0                   (log2 units)
    float sl1 = 0.f;   // sum frac*(T1-T0)         (log2 units)

    if (ib != jb) {
        #pragma unroll 8
        for (int k = 0; k < TI; ++k) {
            const float pj = pj_base[k];             // uniform -> scalar load
            const float tj = tj_base[k];
            const float d  = __builtin_fmaf(pj, -SCALE, pi);
            const float am = fminf(fabsf(d), CLAMPV);
            const unsigned idx = (unsigned)am;       // trunc
            const float fr = am - (float)idx;
            const float T0 = tbl[idx];
            const float T1 = tbl[idx + 1];
            sl0 += T0;
            sl1 = __builtin_fmaf(fr, T1 - T0, sl1);
            const float sdv = (ti < tj) ? d : -d;
            st += fminf(sdv, 0.f);
        }
    } else {
        #pragma unroll 8
        for (int k = 0; k < TI; ++k) {
            const float pj = pj_base[k];
            const float tj = tj_base[k];
            const bool valid = (k > tid);
            float d  = __builtin_fmaf(pj, -SCALE, pi);
            float am = fminf(fabsf(d), CLAMPV);
            am = valid ? am : CLAMPV;                // invalid -> ~2e-5 leak (negligible)
            d  = valid ? d : 0.f;                    // invalid -> sd term 0
            const unsigned idx = (unsigned)am;
            const float fr = am - (float)idx;
            const float T0 = tbl[idx];
            const float T1 = tbl[idx + 1];
            sl0 += T0;
            sl1 = __builtin_fmaf(fr, T1 - T0, sl1);
            const float sdv = (ti < tj) ? d : -d;
            st += fminf(sdv, 0.f);
        }
    }

    float stt = st;
    float sll = sl0 + sl1;
    for (int off = 32; off > 0; off >>= 1) {
        stt += __shfl_down(stt, off, 64);
        sll += __shfl_down(sll, off, 64);
    }
    __shared__ float wt[TI / 64], wl[TI / 64];
    const int wave = tid >> 6;
    if ((tid & 63) == 0) { wt[wave] = stt; wl[wave] = sll; }
    __syncthreads();
    if (tid == 0) pout[blockIdx.x] = make_float2(wt[0] + wt[1], wl[0] + wl[1]);
}

__global__ __launch_bounds__(256) void rankloss_final(
    const float2* __restrict__ pout, float* __restrict__ out)
{
    const int tid = threadIdx.x;
    double st = 0.0, sl = 0.0;
    for (int b = tid; b < NTILES; b += 256) {
        const float2 v = pout[b];
        st += (double)v.x;
        sl += (double)v.y;
    }
    for (int off = 32; off > 0; off >>= 1) {
        st += __shfl_down(st, off, 64);
        sl += __shfl_down(sl, off, 64);
    }
    __shared__ double wst[4], wsl[4];
    const int wave = tid >> 6;
    if ((tid & 63) == 0) { wst[wave] = st; wsl[wave] = sl; }
    __syncthreads();
    if (tid == 0) {
        double St = 0.0, Sl = 0.0;
        #pragma unroll
        for (int w = 0; w < 4; ++w) { St += wst[w]; Sl += wsl[w]; }
        const double count = 33550336.0;              // C(8192,2)
        const double ln2   = 0.6931471805599453;
        out[0] = (float)((St * (ln2 / 32.0) - Sl * ln2) / count);
    }
}

extern "C" void kernel_launch(void* const* d_in, const int* in_sizes, int n_in,
                              void* d_out, int out_size, void* d_ws, size_t ws_size,
                              hipStream_t stream) {
    const float* preds = (const float*)d_in[0];
    const float* tgts  = (const float*)d_in[1];
    float2* pout = (float2*)d_ws;   // NTILES float2 = 16.6 KB, fully written by tri

    rankloss_tri<<<NTILES, TI, 0, stream>>>(preds, tgts, pout);
    rankloss_final<<<1, 256, 0, stream>>>(pout, (float*)d_out);
}

// Round 9
// 67.348 us; speedup vs baseline: 1.1124x; 1.0644x over previous
//
#include <hip/hip_runtime.h>

// RankLoss via signed softplus table, nearest-neighbor (no interp, 1 gather).
//   reference: for pairs (i,j) with tg[i] < tg[j]: sum log_sigmoid(p[i]-p[j]).
//   Per unordered pair {i,j} exactly one direction fires (ties measure-zero):
//     term = log_sigmoid(sd) = -ln(1+e^{-sd}),  sd = (tg_i<tg_j ? d : -d).
//   Work in scaled units d' = d*16*log2e:  e^{-sd} = 2^{-sd'/16}.
//   Table T[k] = ln(1+2^{(k-256)/16}), k in [0,512]; lookup k = round(256 - sd').
//   Nearest-neighbor bias <= 3e-5 (threshold 1.8e-2). T[513] = 0 (diag-invalid sink).
//   count = C(8192,2) analytic.
// Inner loop: 8 VALU + 1 ds_read, single accumulator (R8 had ~13 VALU + 2 ds_read).

#define N 8192
#define TI 128
#define NB (N / TI)                  // 64
#define NTILES (NB * (NB + 1) / 2)   // 2080
#define SCALE2 23.083120654223414f   // 16*log2(e)
#define TBLN 514                     // 0..512 table + [513]=0 sink

__global__ __launch_bounds__(TI) void rankloss_tri(
    const float* __restrict__ preds, const float* __restrict__ tgts,
    float* __restrict__ pout)
{
    __shared__ float tbl[TBLN];
    const int tid = threadIdx.x;
    const int u = blockIdx.x;

    // build T[k] = ln(1 + 2^{(k-256)/16}); T[513] = 0
    for (int k = tid; k < TBLN; k += TI) {
        const float a = (float)(k - 256) * (1.0f / 16.0f);
        tbl[k] = (k == 513) ? 0.0f : __logf(1.0f + __builtin_amdgcn_exp2f(a));
    }

    // decode triangular tile index: u = jb*(jb+1)/2 + ib, ib <= jb
    int jb = (int)((sqrtf(8.0f * (float)u + 1.0f) - 1.0f) * 0.5f);
    while ((jb + 1) * (jb + 2) / 2 <= u) ++jb;
    while (jb * (jb + 1) / 2 > u) --jb;
    const int ib = u - jb * (jb + 1) / 2;

    const int i  = ib * TI + tid;
    const int j0 = jb * TI;

    const float xi = preds[i] * SCALE2;    // i-value, scaled units
    const float ti = tgts[i];
    const float* __restrict__ pj_base = preds + j0;   // block-uniform -> s_load
    const float* __restrict__ tj_base = tgts  + j0;

    __syncthreads();   // table ready

    const float HI = 512.9f;        // clamp hi (idx <= 512)
    const float SINK = 513.25f;     // diag-invalid -> T[513] = 0
    float acc = 0.f;                // sum of T = sum softplus(-sd) = -sum logsig

    if (ib != jb) {
        #pragma unroll 8
        for (int k = 0; k < TI; ++k) {
            const float pj = pj_base[k];                        // uniform
            const float tj = tj_base[k];
            const float d  = __builtin_fmaf(pj, -SCALE2, xi);   // d' = (pi-pj)*s
            const float sd = (ti < tj) ? d : -d;
            float y = 256.5f - sd;                              // +0.5 folds round
            y = fminf(fmaxf(y, 0.5f), HI);                      // v_med3_f32
            acc += tbl[(unsigned)y];                            // trunc = round
        }
    } else {
        // diagonal tile: only j = k > i = tid valid; invalid -> T[513]=0
        #pragma unroll 8
        for (int k = 0; k < TI; ++k) {
            const float pj = pj_base[k];
            const float tj = tj_base[k];
            const float d  = __builtin_fmaf(pj, -SCALE2, xi);
            const float sd = (ti < tj) ? d : -d;
            float y = 256.5f - sd;
            y = fminf(fmaxf(y, 0.5f), HI);
            y = (k > tid) ? y : SINK;
            acc += tbl[(unsigned)y];
        }
    }

    for (int off = 32; off > 0; off >>= 1)
        acc += __shfl_down(acc, off, 64);

    __shared__ float wacc[TI / 64];
    const int wave = tid >> 6;
    if ((tid & 63) == 0) wacc[wave] = acc;
    __syncthreads();
    if (tid == 0) pout[blockIdx.x] = wacc[0] + wacc[1];
}

__global__ __launch_bounds__(256) void rankloss_final(
    const float* __restrict__ pout, float* __restrict__ out)
{
    const int tid = threadIdx.x;
    double s = 0.0;
    for (int b = tid; b < NTILES; b += 256)
        s += (double)pout[b];
    for (int off = 32; off > 0; off >>= 1)
        s += __shfl_down(s, off, 64);
    __shared__ double ws[4];
    const int wave = tid >> 6;
    if ((tid & 63) == 0) ws[wave] = s;
    __syncthreads();
    if (tid == 0) {
        double S = ws[0] + ws[1] + ws[2] + ws[3];
        const double count = 33550336.0;   // C(8192,2)
        out[0] = (float)(-S / count);
    }
}

extern "C" void kernel_launch(void* const* d_in, const int* in_sizes, int n_in,
                              void* d_out, int out_size, void* d_ws, size_t ws_size,
                              hipStream_t stream) {
    const float* preds = (const float*)d_in[0];
    const float* tgts  = (const float*)d_in[1];
    float* pout = (float*)d_ws;   // NTILES floats = 8.3 KB, fully written by tri

    rankloss_tri<<<NTILES, TI, 0, stream>>>(preds, tgts, pout);
    rankloss_final<<<1, 256, 0, stream>>>(pout, (float*)d_out);
}